// Round 2
// baseline (2923.016 us; speedup 1.0000x reference)
//
#include <hip/hip_runtime.h>
#include <math.h>

// ---------------- problem constants ----------------
#define BB 2
#define QQ 2048
#define HH 64
#define WW 64
#define CC 64          // encoder channels
#define CF 576         // unfolded channels (64*9)
#define K0 578         // MLP input dim
#define NMID 256
#define NOUT 27
#define NOFF 36
#define NBQ (BB*QQ)    // 4096
#define NROWS (NOFF*NBQ)  // 147456

// padded feature map: [b][66][66][64]
#define FEAT_ELEMS (BB*66*66*CC)       // 557568

// ---------------- kernel 1: conv 3x3, 3->64, into padded NHWC ----------------
__global__ __launch_bounds__(256) void k_conv(const float* __restrict__ inp,
                                              const float* __restrict__ ew,
                                              const float* __restrict__ eb,
                                              float* __restrict__ feat) {
    int idx = blockIdx.x * 256 + threadIdx.x;
    if (idx >= FEAT_ELEMS) return;
    int c = idx & 63;
    int t = idx >> 6;
    int x = t % 66; t /= 66;
    int y = t % 66;
    int b = t / 66;
    float v = 0.f;
    if (y >= 1 && y <= 64 && x >= 1 && x <= 64) {
        int yr = y - 1, xr = x - 1;
        v = eb[c];
        #pragma unroll
        for (int i = 0; i < 3; ++i) {
            #pragma unroll
            for (int ky = 0; ky < 3; ++ky) {
                int yy = yr + ky - 1;
                if (yy < 0 || yy > 63) continue;
                #pragma unroll
                for (int kx = 0; kx < 3; ++kx) {
                    int xx = xr + kx - 1;
                    if (xx < 0 || xx > 63) continue;
                    v = fmaf(inp[((b*3 + i)*64 + yy)*64 + xx],
                             ew[((c*3 + i)*3 + ky)*3 + kx], v);
                }
            }
        }
    }
    feat[idx] = v;
}

// ---------------- kernel 2: per-row prep ----------------
// row r = n*4096 + (b*2048+q). Computes rel[18], area, gather base offset.
__global__ __launch_bounds__(256) void k_prep(const float* __restrict__ coord,
                                              float* __restrict__ relw,
                                              float* __restrict__ areaw,
                                              int* __restrict__ iposw) {
    int r = blockIdx.x * 256 + threadIdx.x;
    if (r >= NROWS) return;
    int n  = r >> 12;
    int bq = r & 4095;
    const float offs[6] = {-3.f, -2.f, -1.f, 1.f, 2.f, 3.f};
    float vx = offs[n / 6];
    float vy = offs[n % 6];
    const float* cp = coord + bq * 18;
    float cc0 = cp[8] + vx * (1.0f/64.0f) + 1e-6f;
    float cc1 = cp[9] + vy * (1.0f/64.0f) + 1e-6f;
    cc0 = fminf(fmaxf(cc0, -1.f + 1e-6f), 1.f - 1e-6f);
    cc1 = fminf(fmaxf(cc1, -1.f + 1e-6f), 1.f - 1e-6f);
    // round-half-to-even matches jnp.round / np.round
    int iy = (int)rintf(((cc0 + 1.f) * 64.f - 1.f) * 0.5f);
    int ix = (int)rintf(((cc1 + 1.f) * 64.f - 1.f) * 0.5f);
    iy = min(max(iy, 0), 63);
    ix = min(max(ix, 0), 63);
    float qc0 = -1.f + (2.f * (float)iy + 1.f) * (1.0f/64.0f);
    float qc1 = -1.f + (2.f * (float)ix + 1.f) * (1.0f/64.0f);
    float rel0 = 0.f, rel1 = 0.f;
    #pragma unroll
    for (int d = 0; d < 18; ++d) {
        float qc = (d & 1) ? qc1 : qc0;
        float sc = (d & 1) ? 1.f : 4096.f;
        float rv = (cp[d] - qc) * sc;
        relw[r*18 + d] = rv;
        if (d == 0) rel0 = rv;
        if (d == 1) rel1 = rv;
    }
    areaw[r] = fabsf(rel0 * rel1) + 1e-9f;
    int b = bq >> 11;
    iposw[r] = ((b*66 + iy)*66 + ix) * 64;
}

// ---------------- kernel 3: per-(b,q) area totals ----------------
__global__ __launch_bounds__(256) void k_tot(const float* __restrict__ areaw,
                                             float* __restrict__ totw) {
    int i = blockIdx.x * 256 + threadIdx.x;
    if (i >= NBQ) return;
    float s = 0.f;
    #pragma unroll
    for (int n = 0; n < NOFF; ++n) s += areaw[n*NBQ + i];
    totw[i] = s;
}

// ---------------- kernel 4: fused MLP per (b,q) ----------------
// 256 threads: thread = (cg=tid&63 -> 4 cols, rg=tid>>6 -> 9 rows). acc[9][4].
#define XP 292   // LDS X pitch (floats)

__device__ __forceinline__ void fma4(float xc, float4 wv, float* a) {
    a[0] = fmaf(xc, wv.x, a[0]);
    a[1] = fmaf(xc, wv.y, a[1]);
    a[2] = fmaf(xc, wv.z, a[2]);
    a[3] = fmaf(xc, wv.w, a[3]);
}

__device__ __forceinline__ void gemm_stages(const float* __restrict__ Wg, int kOff, int kValid,
                                            int nStages, int Klimit,
                                            const float* sIn, int inPitch,
                                            float* s_w, float acc[9][4],
                                            int tid, int r0, int c0) {
    for (int st = 0; st < nStages; ++st) {
        int kbase = st * 16;
        __syncthreads();
        #pragma unroll
        for (int m = 0; m < 16; ++m) {
            int kg = kOff + kbase + m;
            s_w[m*256 + tid] = (kg < kValid) ? Wg[kg*256 + tid] : 0.f;
        }
        __syncthreads();
        #pragma unroll
        for (int qd = 0; qd < 4; ++qd) {
            int kl = kbase + qd * 4;
            if (kl >= Klimit) break;
            float4 wv0 = *(const float4*)&s_w[(qd*4 + 0)*256 + c0];
            float4 wv1 = *(const float4*)&s_w[(qd*4 + 1)*256 + c0];
            float4 wv2 = *(const float4*)&s_w[(qd*4 + 2)*256 + c0];
            float4 wv3 = *(const float4*)&s_w[(qd*4 + 3)*256 + c0];
            #pragma unroll
            for (int rr = 0; rr < 9; ++rr) {
                float4 xv = *(const float4*)&sIn[(r0 + rr)*inPitch + kl];
                float* a = acc[rr];
                fma4(xv.x, wv0, a);
                fma4(xv.y, wv1, a);
                fma4(xv.z, wv2, a);
                fma4(xv.w, wv3, a);
            }
        }
    }
}

template <int J0, int NC>
__device__ __forceinline__ void build_x(float* s_x, const float* __restrict__ feat,
                                        const int* s_ipos, const float* s_rel,
                                        const float* s_div, const float* s_cell,
                                        int tid) {
    for (int idx = tid; idx < NOFF * NC; idx += 256) {
        int r = idx / NC;
        int j = J0 + (idx - r * NC);
        float val;
        if (j < CF) {
            int c = j / 9;
            int s = j - c * 9;
            int di = s / 3, dj = s - di * 3;
            val = feat[s_ipos[r] + (di*66 + dj)*64 + c];
            int k = j >> 6, d = j & 63;
            float comp = s_rel[r*18 + 2*k + (d >> 5)];
            int t = (d & 31) >> 1;
            float arg = comp * s_div[t];
            val += (d & 1) ? cosf(arg) : sinf(arg);
        } else {
            val = s_cell[j - CF];
        }
        s_x[r*XP + (j - J0)] = val;
    }
}

__global__ __launch_bounds__(256) void k_mlp(const float* __restrict__ cellp,
                                             const float* __restrict__ w0, const float* __restrict__ b0,
                                             const float* __restrict__ w1, const float* __restrict__ b1,
                                             const float* __restrict__ w2, const float* __restrict__ b2,
                                             const float* __restrict__ w3, const float* __restrict__ b3,
                                             const float* __restrict__ w4, const float* __restrict__ b4,
                                             const float* __restrict__ feat,
                                             const float* __restrict__ relw,
                                             const float* __restrict__ areaw,
                                             const float* __restrict__ totw,
                                             const int* __restrict__ iposw,
                                             float* __restrict__ out) {
    __shared__ float s_x[NOFF * XP];      // X tile; reused as activation buffer
    __shared__ float s_a1[NOFF * 256];
    __shared__ float s_w[16 * 256];
    __shared__ float s_rel[NOFF * 18];
    __shared__ float s_pred[NOFF * 28];
    __shared__ float s_wgt[NOFF];
    __shared__ float s_div[16];
    __shared__ float s_cell[2];
    __shared__ int   s_ipos[NOFF];

    int tid = threadIdx.x;
    int bq  = blockIdx.x;   // b*2048 + q

    if (tid < 16) s_div[tid] = expf((float)(2*tid) * -0.28782313662425575f);
    if (tid < 2)  s_cell[tid] = cellp[bq*2 + tid] * 64.0f;
    if (tid < NOFF) {
        int pn = tid < 4 ? 3 - tid : tid;
        s_wgt[tid]  = areaw[pn*NBQ + bq] / totw[bq];
        s_ipos[tid] = iposw[tid*NBQ + bq];
    }
    for (int i = tid; i < NOFF*18; i += 256) {
        int n = i / 18, d = i - n*18;
        s_rel[i] = relw[(n*NBQ + bq)*18 + d];
    }

    int cg = tid & 63, rg = tid >> 6;
    int r0 = rg * 9, c0 = cg * 4;

    float acc[9][4];
    #pragma unroll
    for (int rr = 0; rr < 9; ++rr)
        #pragma unroll
        for (int cc = 0; cc < 4; ++cc) acc[rr][cc] = 0.f;

    // ---- layer 0 (K=578) in two halves to bound LDS ----
    __syncthreads();
    build_x<0, 288>(s_x, feat, s_ipos, s_rel, s_div, s_cell, tid);
    gemm_stages(w0, 0, K0, 18, 288, s_x, XP, s_w, acc, tid, r0, c0);

    __syncthreads();   // all half-0 reads done before overwrite
    build_x<288, 290>(s_x, feat, s_ipos, s_rel, s_div, s_cell, tid);
    if (tid < NOFF) { s_x[tid*XP + 290] = 0.f; s_x[tid*XP + 291] = 0.f; }
    gemm_stages(w0, 288, K0, 19, 292, s_x, XP, s_w, acc, tid, r0, c0);

    // epilogue L0 -> s_a1
    {
        float4 bv = *(const float4*)&b0[c0];
        #pragma unroll
        for (int rr = 0; rr < 9; ++rr) {
            float4 o;
            o.x = fmaxf(acc[rr][0] + bv.x, 0.f);
            o.y = fmaxf(acc[rr][1] + bv.y, 0.f);
            o.z = fmaxf(acc[rr][2] + bv.z, 0.f);
            o.w = fmaxf(acc[rr][3] + bv.w, 0.f);
            *(float4*)&s_a1[(r0 + rr)*256 + c0] = o;
        }
    }

    // ---- layers 1..3 (K=256), ping-pong s_a1 <-> s_x ----
    const float* Ws[3] = {w1, w2, w3};
    const float* Bs[3] = {b1, b2, b3};
    for (int L = 0; L < 3; ++L) {
        const float* sin_ = (L & 1) ? s_x : s_a1;
        float*       sout = (L & 1) ? s_a1 : s_x;
        #pragma unroll
        for (int rr = 0; rr < 9; ++rr)
            #pragma unroll
            for (int cc = 0; cc < 4; ++cc) acc[rr][cc] = 0.f;
        gemm_stages(Ws[L], 0, 256, 16, 256, sin_, 256, s_w, acc, tid, r0, c0);
        float4 bv = *(const float4*)&Bs[L][c0];
        #pragma unroll
        for (int rr = 0; rr < 9; ++rr) {
            float4 o;
            o.x = fmaxf(acc[rr][0] + bv.x, 0.f);
            o.y = fmaxf(acc[rr][1] + bv.y, 0.f);
            o.z = fmaxf(acc[rr][2] + bv.z, 0.f);
            o.w = fmaxf(acc[rr][3] + bv.w, 0.f);
            *(float4*)&sout[(r0 + rr)*256 + c0] = o;
        }
    }
    // after L3, activations are in s_x (pitch 256)
    __syncthreads();

    // ---- layer 4 (256 -> 27) + weighting ----
    #pragma unroll
    for (int i = 0; i < 4; ++i) {
        int o = tid + i*256;
        if (o < NOFF * NOUT) {
            int r = o / NOUT, col = o - r*NOUT;
            float a4 = b4[col];
            for (int k = 0; k < 256; k += 4) {
                float4 av = *(const float4*)&s_x[r*256 + k];
                a4 = fmaf(av.x, w4[(k+0)*NOUT + col], a4);
                a4 = fmaf(av.y, w4[(k+1)*NOUT + col], a4);
                a4 = fmaf(av.z, w4[(k+2)*NOUT + col], a4);
                a4 = fmaf(av.w, w4[(k+3)*NOUT + col], a4);
            }
            s_pred[r*28 + col] = a4 * s_wgt[r];
        }
    }
    __syncthreads();
    if (tid < NOUT) {
        float s = 0.f;
        #pragma unroll
        for (int r = 0; r < NOFF; ++r) s += s_pred[r*28 + tid];
        out[bq*NOUT + tid] = s;
    }
}

// ---------------- launch ----------------
extern "C" void kernel_launch(void* const* d_in, const int* in_sizes, int n_in,
                              void* d_out, int out_size, void* d_ws, size_t ws_size,
                              hipStream_t stream) {
    const float* inp   = (const float*)d_in[0];
    const float* coord = (const float*)d_in[1];
    const float* cellp = (const float*)d_in[2];
    const float* enc_w = (const float*)d_in[3];
    const float* enc_b = (const float*)d_in[4];
    const float* w0 = (const float*)d_in[5];
    const float* b0 = (const float*)d_in[6];
    const float* w1 = (const float*)d_in[7];
    const float* b1 = (const float*)d_in[8];
    const float* w2 = (const float*)d_in[9];
    const float* b2 = (const float*)d_in[10];
    const float* w3 = (const float*)d_in[11];
    const float* b3 = (const float*)d_in[12];
    const float* w4 = (const float*)d_in[13];
    const float* b4 = (const float*)d_in[14];
    float* outp = (float*)d_out;

    float* ws    = (float*)d_ws;
    float* feat  = ws;                      // FEAT_ELEMS
    float* relw  = feat + FEAT_ELEMS;       // NROWS*18
    float* areaw = relw + (size_t)NROWS*18; // NROWS
    float* totw  = areaw + NROWS;           // NBQ
    int*   iposw = (int*)(totw + NBQ);      // NROWS

    k_conv<<<(FEAT_ELEMS + 255)/256, 256, 0, stream>>>(inp, enc_w, enc_b, feat);
    k_prep<<<NROWS/256, 256, 0, stream>>>(coord, relw, areaw, iposw);
    k_tot<<<(NBQ + 255)/256, 256, 0, stream>>>(areaw, totw);
    k_mlp<<<NBQ, 256, 0, stream>>>(cellp, w0, b0, w1, b1, w2, b2, w3, b3, w4, b4,
                                   feat, relw, areaw, totw, iposw, outp);
}

// Round 3
// 461.399 us; speedup vs baseline: 6.3351x; 6.3351x over previous
//
#include <hip/hip_runtime.h>
#include <math.h>

typedef _Float16 f16;
typedef f16 f16x8 __attribute__((ext_vector_type(8)));
typedef f16 f16x2 __attribute__((ext_vector_type(2)));
typedef float f32x4 __attribute__((ext_vector_type(4)));

// ---------------- problem constants ----------------
#define BB 2
#define QQ 2048
#define CF 576
#define NOFF 36
#define NBQ (BB*QQ)          // 4096
#define NROWS (NOFF*NBQ)     // 147456  (row R = bq*36 + n)
#define FEAT_ELEMS (BB*66*66*64)
#define KP0 608              // layer-0 K padded (578 -> 608)
#define MROWS 96             // rows per workgroup
#define NWG (NROWS/MROWS)    // 1536
#define PITCH 320            // halfs per LDS row (byte pitch 640)

// ---------------- kernel 1: conv 3x3, 3->64, padded NHWC ----------------
__global__ __launch_bounds__(256) void k_conv(const float* __restrict__ inp,
                                              const float* __restrict__ ew,
                                              const float* __restrict__ eb,
                                              float* __restrict__ feat) {
    int idx = blockIdx.x * 256 + threadIdx.x;
    if (idx >= FEAT_ELEMS) return;
    int c = idx & 63;
    int t = idx >> 6;
    int x = t % 66; t /= 66;
    int y = t % 66;
    int b = t / 66;
    float v = 0.f;
    if (y >= 1 && y <= 64 && x >= 1 && x <= 64) {
        int yr = y - 1, xr = x - 1;
        v = eb[c];
        #pragma unroll
        for (int i = 0; i < 3; ++i)
            #pragma unroll
            for (int ky = 0; ky < 3; ++ky) {
                int yy = yr + ky - 1;
                if (yy < 0 || yy > 63) continue;
                #pragma unroll
                for (int kx = 0; kx < 3; ++kx) {
                    int xx = xr + kx - 1;
                    if (xx < 0 || xx > 63) continue;
                    v = fmaf(inp[((b*3 + i)*64 + yy)*64 + xx],
                             ew[((c*3 + i)*3 + ky)*3 + kx], v);
                }
            }
    }
    feat[idx] = v;
}

// ---------------- kernel 2: weight convert fp32 -> fp16 transposed ----------------
// Wt0[256][608], Wt1..3[256][256], Wt4[32][256] (cols 27..31 zero)
__global__ __launch_bounds__(256) void k_wcvt(const float* __restrict__ w0,
                                              const float* __restrict__ w1,
                                              const float* __restrict__ w2,
                                              const float* __restrict__ w3,
                                              const float* __restrict__ w4,
                                              f16* __restrict__ wt0, f16* __restrict__ wt1,
                                              f16* __restrict__ wt2, f16* __restrict__ wt3,
                                              f16* __restrict__ wt4) {
    int i = blockIdx.x * 256 + threadIdx.x;
    if (i < 256*608) {
        int n = i / 608, k = i - n*608;
        wt0[i] = (f16)((k < 578) ? w0[k*256 + n] : 0.f);
        return;
    }
    i -= 256*608;
    if (i < 3*65536) {
        int l = i >> 16, j = i & 65535;
        int n = j >> 8, k = j & 255;
        const float* w = (l == 0) ? w1 : (l == 1) ? w2 : w3;
        f16* wt = (l == 0) ? wt1 : (l == 1) ? wt2 : wt3;
        wt[j] = (f16)w[k*256 + n];
        return;
    }
    i -= 3*65536;
    if (i < 32*256) {
        int n = i >> 8, k = i & 255;
        wt4[i] = (f16)((n < 27) ? w4[k*27 + n] : 0.f);
    }
}

// ---------------- kernel 3: per-row prep (R = bq*36 + n) ----------------
__global__ __launch_bounds__(256) void k_prep(const float* __restrict__ coord,
                                              float* __restrict__ qc0w,
                                              float* __restrict__ qc1w,
                                              float* __restrict__ areaw,
                                              int* __restrict__ iposw) {
    int R = blockIdx.x * 256 + threadIdx.x;
    if (R >= NROWS) return;
    int bq = R / 36, n = R - bq*36;
    const float offs[6] = {-3.f, -2.f, -1.f, 1.f, 2.f, 3.f};
    float vx = offs[n / 6];
    float vy = offs[n % 6];
    const float* cp = coord + bq * 18;
    float cc0 = cp[8] + vx * (1.0f/64.0f) + 1e-6f;
    float cc1 = cp[9] + vy * (1.0f/64.0f) + 1e-6f;
    cc0 = fminf(fmaxf(cc0, -1.f + 1e-6f), 1.f - 1e-6f);
    cc1 = fminf(fmaxf(cc1, -1.f + 1e-6f), 1.f - 1e-6f);
    int iy = (int)rintf(((cc0 + 1.f) * 64.f - 1.f) * 0.5f);
    int ix = (int)rintf(((cc1 + 1.f) * 64.f - 1.f) * 0.5f);
    iy = min(max(iy, 0), 63);
    ix = min(max(ix, 0), 63);
    float qc0 = -1.f + (2.f * (float)iy + 1.f) * (1.0f/64.0f);
    float qc1 = -1.f + (2.f * (float)ix + 1.f) * (1.0f/64.0f);
    float rel0 = (cp[0] - qc0) * 4096.f;
    float rel1 = (cp[1] - qc1);
    qc0w[R] = qc0;
    qc1w[R] = qc1;
    areaw[R] = fabsf(rel0 * rel1) + 1e-9f;
    int b = bq >> 11;
    iposw[R] = ((b*66 + iy)*66 + ix) * 64;
}

// ---------------- kernel 4: per-bq weights (perm + normalize) ----------------
__global__ __launch_bounds__(256) void k_wgt(const float* __restrict__ areaw,
                                             float* __restrict__ wgtw) {
    int bq = blockIdx.x * 256 + threadIdx.x;
    if (bq >= NBQ) return;
    float a[36];
    float tot = 0.f;
    #pragma unroll
    for (int n = 0; n < 36; ++n) { a[n] = areaw[bq*36 + n]; tot += a[n]; }
    #pragma unroll
    for (int n = 0; n < 36; ++n) {
        int pn = (n < 4) ? 3 - n : n;
        wgtw[bq*36 + n] = a[pn] / tot;
    }
}

// ---------------- kernel 5: fused MFMA MLP ----------------
__global__ __launch_bounds__(512, 2) void k_mlp(
    const float* __restrict__ coord, const float* __restrict__ cellp,
    const float* __restrict__ feat,
    const float* __restrict__ qc0w, const float* __restrict__ qc1w,
    const float* __restrict__ wgtw, const int* __restrict__ iposw,
    const f16* __restrict__ wt0, const f16* __restrict__ wt1,
    const f16* __restrict__ wt2, const f16* __restrict__ wt3,
    const f16* __restrict__ wt4,
    const float* __restrict__ b0, const float* __restrict__ b1,
    const float* __restrict__ b2, const float* __restrict__ b3,
    const float* __restrict__ b4,
    float* __restrict__ predw)
{
    __shared__ f16 sA[MROWS * PITCH];    // 61440 B
    __shared__ f16 sB[MROWS * PITCH];    // 61440 B
    __shared__ float s_crd[MROWS * 18];
    __shared__ float s_qc0[MROWS], s_qc1[MROWS], s_cx[MROWS], s_cy[MROWS], s_wgt[MROWS];
    __shared__ int   s_ipos[MROWS];
    __shared__ float s_div[16];

    int tid = threadIdx.x;
    int R0  = blockIdx.x * MROWS;

    if (tid < 16) s_div[tid] = expf((float)(2*tid) * -0.28782313662425575f);
    if (tid < MROWS) {
        int R  = R0 + tid;
        int bq = R / 36;
        s_qc0[tid]  = qc0w[R];
        s_qc1[tid]  = qc1w[R];
        s_wgt[tid]  = wgtw[R];
        s_ipos[tid] = iposw[R];
        s_cx[tid]   = cellp[bq*2 + 0] * 64.f;
        s_cy[tid]   = cellp[bq*2 + 1] * 64.f;
    }
    for (int i = tid; i < MROWS*18; i += 512) {
        int r = i / 18, d = i - r*18;
        s_crd[i] = coord[((R0 + r)/36)*18 + d];
    }

    int lane = tid & 63;
    int wid  = tid >> 6;
    int wr   = wid >> 2;    // 0..1  (m group: 48 rows)
    int wc   = wid & 3;     // 0..3  (n group: 64 cols)
    int l15  = lane & 15;
    int lg   = lane >> 4;   // 0..3
    uint aswz = (uint)((lane & 7) << 4);

    uint abase[3];
    #pragma unroll
    for (int mt = 0; mt < 3; ++mt) {
        int row = wr*48 + mt*16 + l15;
        abase[mt] = (uint)(row * (PITCH*2) + lg*16);
    }

    // build X[k0,k1) into sX (paired sin/cos elements)
    auto build = [&](f16* sX, int k0, int k1) {
        int cols2 = (k1 - k0) >> 1;
        int npair = MROWS * cols2;
        for (int p = tid; p < npair; p += 512) {
            int r = p / cols2;
            int j = k0 + ((p - r*cols2) << 1);
            float v0, v1;
            if (j < CF) {
                int c0 = j / 9,  s0 = j  - c0*9;
                int j1 = j + 1;
                int c1 = j1 / 9, s1 = j1 - c1*9;
                int ip = s_ipos[r];
                float f0 = feat[ip + ((s0/3)*66 + (s0 - (s0/3)*3))*64 + c0];
                float f1 = feat[ip + ((s1/3)*66 + (s1 - (s1/3)*3))*64 + c1];
                int d  = j & 63;
                int pl = j >> 6;
                int h2 = d >> 5;
                float qc = h2 ? s_qc1[r] : s_qc0[r];
                float sc = h2 ? 1.f : 4096.f;
                float comp = (s_crd[r*18 + 2*pl + h2] - qc) * sc;
                float arg  = comp * s_div[(d & 31) >> 1];
                v0 = f0 + sinf(arg);
                v1 = f1 + cosf(arg);
            } else if (j == CF) {
                v0 = s_cx[r]; v1 = s_cy[r];
            } else {
                v0 = 0.f; v1 = 0.f;
            }
            uint off = (uint)(r*(PITCH*2) + (j - k0)*2);
            off ^= (uint)((r & 7) << 4);
            f16x2 hv = { (f16)v0, (f16)v1 };
            *(f16x2*)((char*)sX + off) = hv;
        }
    };

    f32x4 acc[3][4];
    auto zacc = [&]() {
        #pragma unroll
        for (int mt = 0; mt < 3; ++mt)
            #pragma unroll
            for (int nt = 0; nt < 4; ++nt)
                #pragma unroll
                for (int i = 0; i < 4; ++i) acc[mt][nt][i] = 0.f;
    };

    // GEMM over nks k-steps; A from LDS (swizzled), B from global (prefetched)
    auto gemm = [&](const f16* sX, const f16* __restrict__ Wt, int wtPitch, int ks0, int nks) {
        f16x8 a[3], b[4], an[3], bn[4];
        #pragma unroll
        for (int mt = 0; mt < 3; ++mt)
            a[mt] = *(const f16x8*)((const char*)sX + ((abase[mt] + 0u) ^ aswz));
        #pragma unroll
        for (int nt = 0; nt < 4; ++nt) {
            int col = wc*64 + nt*16 + l15;
            b[nt] = *(const f16x8*)(Wt + (size_t)col*wtPitch + (size_t)(ks0)*32 + lg*8);
        }
        for (int ks = 0; ks < nks; ++ks) {
            int ksn = (ks + 1 < nks) ? ks + 1 : ks;
            #pragma unroll
            for (int mt = 0; mt < 3; ++mt)
                an[mt] = *(const f16x8*)((const char*)sX + ((abase[mt] + (uint)(ksn*64)) ^ aswz));
            #pragma unroll
            for (int nt = 0; nt < 4; ++nt) {
                int col = wc*64 + nt*16 + l15;
                bn[nt] = *(const f16x8*)(Wt + (size_t)col*wtPitch + (size_t)(ks0 + ksn)*32 + lg*8);
            }
            #pragma unroll
            for (int mt = 0; mt < 3; ++mt)
                #pragma unroll
                for (int nt = 0; nt < 4; ++nt)
                    acc[mt][nt] = __builtin_amdgcn_mfma_f32_16x16x32_f16(a[mt], b[nt], acc[mt][nt], 0, 0, 0);
            #pragma unroll
            for (int mt = 0; mt < 3; ++mt) a[mt] = an[mt];
            #pragma unroll
            for (int nt = 0; nt < 4; ++nt) b[nt] = bn[nt];
        }
    };

    // bias + relu + fp16 -> swizzled LDS out
    auto epi = [&](const float* __restrict__ bias, f16* sOut) {
        #pragma unroll
        for (int nt = 0; nt < 4; ++nt) {
            int col = wc*64 + nt*16 + l15;
            float bv = bias[col];
            #pragma unroll
            for (int mt = 0; mt < 3; ++mt)
                #pragma unroll
                for (int i = 0; i < 4; ++i) {
                    int row = wr*48 + mt*16 + lg*4 + i;
                    float v = fmaxf(acc[mt][nt][i] + bv, 0.f);
                    uint off = (uint)(row*(PITCH*2) + col*2) ^ (uint)((row & 7) << 4);
                    *(f16*)((char*)sOut + off) = (f16)v;
                }
        }
    };

    __syncthreads();

    // ---- layer 0 : K = 608 in two LDS chunks ----
    zacc();
    build(sA, 0, 320);
    __syncthreads();
    gemm(sA, wt0, KP0, 0, 10);
    __syncthreads();
    build(sA, 320, KP0);
    __syncthreads();
    gemm(sA, wt0, KP0, 10, 9);
    epi(b0, sB);
    __syncthreads();

    // ---- layers 1..3 : K = 256 ----
    zacc(); gemm(sB, wt1, 256, 0, 8); epi(b1, sA); __syncthreads();
    zacc(); gemm(sA, wt2, 256, 0, 8); epi(b2, sB); __syncthreads();
    zacc(); gemm(sB, wt3, 256, 0, 8); epi(b3, sA); __syncthreads();

    // ---- layer 4 : 256 -> 27 (padded 32), waves with wc==0 only ----
    if (wc == 0) {
        f32x4 a4[3][2];
        #pragma unroll
        for (int mt = 0; mt < 3; ++mt)
            #pragma unroll
            for (int nt = 0; nt < 2; ++nt)
                #pragma unroll
                for (int i = 0; i < 4; ++i) a4[mt][nt][i] = 0.f;
        for (int ks = 0; ks < 8; ++ks) {
            f16x8 a[3], b[2];
            #pragma unroll
            for (int mt = 0; mt < 3; ++mt)
                a[mt] = *(const f16x8*)((const char*)sA + ((abase[mt] + (uint)(ks*64)) ^ aswz));
            #pragma unroll
            for (int nt = 0; nt < 2; ++nt) {
                int col = nt*16 + l15;
                b[nt] = *(const f16x8*)(wt4 + (size_t)col*256 + ks*32 + lg*8);
            }
            #pragma unroll
            for (int mt = 0; mt < 3; ++mt)
                #pragma unroll
                for (int nt = 0; nt < 2; ++nt)
                    a4[mt][nt] = __builtin_amdgcn_mfma_f32_16x16x32_f16(a[mt], b[nt], a4[mt][nt], 0, 0, 0);
        }
        #pragma unroll
        for (int nt = 0; nt < 2; ++nt) {
            int col = nt*16 + l15;
            if (col < 27) {
                float bv = b4[col];
                #pragma unroll
                for (int mt = 0; mt < 3; ++mt)
                    #pragma unroll
                    for (int i = 0; i < 4; ++i) {
                        int row = wr*48 + mt*16 + lg*4 + i;
                        float v = (a4[mt][nt][i] + bv) * s_wgt[row];
                        predw[(size_t)(R0 + row)*28 + col] = v;
                    }
            }
        }
    }
}

// ---------------- kernel 6: reduce 36 offsets -> out ----------------
__global__ __launch_bounds__(256) void k_red(const float* __restrict__ predw,
                                             float* __restrict__ out) {
    int i = blockIdx.x * 256 + threadIdx.x;
    if (i >= NBQ * 27) return;
    int bq = i / 27, c = i - bq*27;
    float s = 0.f;
    #pragma unroll
    for (int n = 0; n < 36; ++n)
        s += predw[(size_t)(bq*36 + n)*28 + c];
    out[i] = s;
}

// ---------------- launch ----------------
extern "C" void kernel_launch(void* const* d_in, const int* in_sizes, int n_in,
                              void* d_out, int out_size, void* d_ws, size_t ws_size,
                              hipStream_t stream) {
    const float* inp   = (const float*)d_in[0];
    const float* coord = (const float*)d_in[1];
    const float* cellp = (const float*)d_in[2];
    const float* enc_w = (const float*)d_in[3];
    const float* enc_b = (const float*)d_in[4];
    const float* w0 = (const float*)d_in[5];
    const float* b0 = (const float*)d_in[6];
    const float* w1 = (const float*)d_in[7];
    const float* b1 = (const float*)d_in[8];
    const float* w2 = (const float*)d_in[9];
    const float* b2 = (const float*)d_in[10];
    const float* w3 = (const float*)d_in[11];
    const float* b3 = (const float*)d_in[12];
    const float* w4 = (const float*)d_in[13];
    const float* b4 = (const float*)d_in[14];
    float* outp = (float*)d_out;

    float* ws    = (float*)d_ws;
    float* feat  = ws;                        // 557,568 f32
    float* qc0w  = feat + FEAT_ELEMS;         // 147,456
    float* qc1w  = qc0w + NROWS;              // 147,456
    float* areaw = qc1w + NROWS;              // 147,456
    float* wgtw  = areaw + NROWS;             // 147,456
    int*   iposw = (int*)(wgtw + NROWS);      // 147,456
    float* predw = (float*)(iposw + NROWS);   // 147,456*28
    f16*   wt0   = (f16*)(predw + (size_t)NROWS*28);  // 256*608 halfs
    f16*   wt1   = wt0 + 256*608;
    f16*   wt2   = wt1 + 65536;
    f16*   wt3   = wt2 + 65536;
    f16*   wt4   = wt3 + 65536;               // 32*256 halfs

    k_conv<<<(FEAT_ELEMS + 255)/256, 256, 0, stream>>>(inp, enc_w, enc_b, feat);
    k_wcvt<<<1408, 256, 0, stream>>>(w0, w1, w2, w3, w4, wt0, wt1, wt2, wt3, wt4);
    k_prep<<<NROWS/256, 256, 0, stream>>>(coord, qc0w, qc1w, areaw, iposw);
    k_wgt<<<(NBQ + 255)/256, 256, 0, stream>>>(areaw, wgtw);
    k_mlp<<<NWG, 512, 0, stream>>>(coord, cellp, feat, qc0w, qc1w, wgtw, iposw,
                                   wt0, wt1, wt2, wt3, wt4,
                                   b0, b1, b2, b3, b4, predw);
    k_red<<<(NBQ*27 + 255)/256, 256, 0, stream>>>(predw, outp);
}